// Round 3
// baseline (288.173 us; speedup 1.0000x reference)
//
#include <hip/hip_runtime.h>

#define SEQ 4096
#define DM  1024
#define DH  64
#define NB  4
#define SLOTS_PER_B 288   // sum_{qt=0}^{63} ceil((qt+1)/8)

typedef __attribute__((ext_vector_type(4))) float  f32x4;
typedef __attribute__((ext_vector_type(8))) __bf16 bf16x8;

__device__ __forceinline__ unsigned short f2bf(float f) {
    unsigned int u = __float_as_uint(f);
    u += 0x7FFFu + ((u >> 16) & 1u);          // RNE
    return (unsigned short)(u >> 16);
}

// native fptrunc -> compiler emits v_cvt_pk_bf16_f32 for pairs (RNE)
__device__ __forceinline__ unsigned short bfc(float f) {
    __bf16 h = (__bf16)f;
    return __builtin_bit_cast(unsigned short, h);
}

__device__ __forceinline__ bf16x8 cvt8(f32x4 lo, f32x4 hi) {
    bf16x8 r;
    r[0] = (__bf16)lo[0]; r[1] = (__bf16)lo[1]; r[2] = (__bf16)lo[2]; r[3] = (__bf16)lo[3];
    r[4] = (__bf16)hi[0]; r[5] = (__bf16)hi[1]; r[6] = (__bf16)hi[2]; r[7] = (__bf16)hi[3];
    return r;
}

__device__ __forceinline__ f32x4 mfma_bf16(bf16x8 a, bf16x8 b, f32x4 c) {
    return __builtin_amdgcn_mfma_f32_16x16x32_bf16(a, b, c, 0, 0, 0);
}

// ---------------------------------------------------------------------------
// W pre-convert: W[64][1024] fp32 -> bf16 in MFMA B-fragment order.
// Wf[which][kc(16)][ks(2)][nt(4)][lane(64)][8], elem = W[nt*16+l16][kc*64+ks*32+quad*8+j]
// ---------------------------------------------------------------------------
__global__ __launch_bounds__(256) void wprep_kernel(
    const float* __restrict__ Wq, const float* __restrict__ Wk, const float* __restrict__ Wv,
    unsigned short* __restrict__ Wf)
{
    const int which = blockIdx.y;
    const int kc    = blockIdx.x;                 // 0..15
    const float* W  = (which == 0) ? Wq : (which == 1) ? Wk : Wv;
    unsigned short* out = Wf + (size_t)which * 65536 + (size_t)kc * 4096;
    const int t = threadIdx.x;
#pragma unroll
    for (int s = t; s < 512; s += 256) {
        const int ks = s >> 8, nt = (s >> 6) & 3, ln = s & 63;
        const int qd = ln >> 4, l = ln & 15;
        const float* src = W + (size_t)(nt * 16 + l) * DM + kc * 64 + ks * 32 + qd * 8;
        f32x4 v0 = *(const f32x4*)src;
        f32x4 v1 = *(const f32x4*)(src + 4);
        *(ushort4*)(out + (size_t)s * 8)     = make_ushort4(bfc(v0[0]), bfc(v0[1]), bfc(v0[2]), bfc(v0[3]));
        *(ushort4*)(out + (size_t)s * 8 + 4) = make_ushort4(bfc(v1[0]), bfc(v1[1]), bfc(v1[2]), bfc(v1[3]));
    }
}

// ---------------------------------------------------------------------------
// Projection: Y = X[16384,1024] @ W[64,1024]^T + b  -> bf16
// BARRIER-FREE / LDS-FREE main loop. Each wave owns a 16-row output tile:
//   A-frag: lane l16=row reads 8 consecutive f32 of its row, converts.
//   B-frag: coalesced 16B/lane load from fragment-layout Wf (L2-resident).
// Waves fully independent -> compiler pipelines loads across unrolled k-loop.
// LDS only in the per-wave epilogue (16x64 tile repack), no __syncthreads.
// ---------------------------------------------------------------------------
__global__ __launch_bounds__(256) void proj_kernel(
    const float* __restrict__ xq, const float* __restrict__ xk, const float* __restrict__ xv,
    const unsigned short* __restrict__ Wf,
    const float* __restrict__ bq, const float* __restrict__ bk, const float* __restrict__ bv,
    unsigned short* __restrict__ qh, unsigned short* __restrict__ kh,
    unsigned short* __restrict__ vhT)
{
    __shared__ unsigned short ot[4][16][72];   // per-wave epilogue tile (disjoint)

    const int which = blockIdx.y;
    const float* X  = (which == 0) ? xq : (which == 1) ? xk : xv;
    const float* Bb = (which == 0) ? bq : (which == 1) ? bk : bv;
    const unsigned short* Wg = Wf + (size_t)which * 65536;

    const int m0   = blockIdx.x * 64;
    const int t    = threadIdx.x;
    const int wv   = t >> 6;
    const int lane = t & 63;
    const int quad = lane >> 4;
    const int l16  = lane & 15;

    const int row = m0 + wv * 16 + l16;
    const float* xrow = X + (size_t)row * DM + quad * 8;
    const unsigned short* wb = Wg + lane * 8;

    f32x4 acc[4];
#pragma unroll
    for (int i = 0; i < 4; ++i) acc[i] = f32x4{0.f, 0.f, 0.f, 0.f};

    // prime X for chunk 0: k = quad*8 + {0..3,4..7} (ks=0), +32 (ks=1)
    f32x4 xa0 = *(const f32x4*)(xrow);
    f32x4 xa1 = *(const f32x4*)(xrow + 4);
    f32x4 xa2 = *(const f32x4*)(xrow + 32);
    f32x4 xa3 = *(const f32x4*)(xrow + 36);

#pragma unroll
    for (int kc = 0; kc < 16; ++kc) {
        // B-fragments for this chunk (coalesced 16B/lane, L2)
        bf16x8 b0 = *(const bf16x8*)(wb + (size_t)kc * 4096);
        bf16x8 b1 = *(const bf16x8*)(wb + (size_t)kc * 4096 + 512);
        bf16x8 b2 = *(const bf16x8*)(wb + (size_t)kc * 4096 + 1024);
        bf16x8 b3 = *(const bf16x8*)(wb + (size_t)kc * 4096 + 1536);
        bf16x8 b4 = *(const bf16x8*)(wb + (size_t)kc * 4096 + 2048);
        bf16x8 b5 = *(const bf16x8*)(wb + (size_t)kc * 4096 + 2560);
        bf16x8 b6 = *(const bf16x8*)(wb + (size_t)kc * 4096 + 3072);
        bf16x8 b7 = *(const bf16x8*)(wb + (size_t)kc * 4096 + 3584);

        // prefetch next chunk's X
        f32x4 xn0, xn1, xn2, xn3;
        if (kc < 15) {
            const float* xp = xrow + (kc + 1) * 64;
            xn0 = *(const f32x4*)(xp);
            xn1 = *(const f32x4*)(xp + 4);
            xn2 = *(const f32x4*)(xp + 32);
            xn3 = *(const f32x4*)(xp + 36);
        }

        bf16x8 a0 = cvt8(xa0, xa1);   // ks=0
        bf16x8 a1 = cvt8(xa2, xa3);   // ks=1

        acc[0] = mfma_bf16(a0, b0, acc[0]);
        acc[1] = mfma_bf16(a0, b1, acc[1]);
        acc[2] = mfma_bf16(a0, b2, acc[2]);
        acc[3] = mfma_bf16(a0, b3, acc[3]);
        acc[0] = mfma_bf16(a1, b4, acc[0]);
        acc[1] = mfma_bf16(a1, b5, acc[1]);
        acc[2] = mfma_bf16(a1, b6, acc[2]);
        acc[3] = mfma_bf16(a1, b7, acc[3]);

        if (kc < 15) { xa0 = xn0; xa1 = xn1; xa2 = xn2; xa3 = xn3; }
    }

    // ---- per-wave epilogue: bias, bf16, repack via private LDS tile ----
    // C-layout: col = l16 (within nt block), row = quad*4 + r
#pragma unroll
    for (int nt = 0; nt < 4; ++nt) {
        float bias = Bb[nt * 16 + l16];
#pragma unroll
        for (int r = 0; r < 4; ++r)
            ot[wv][quad * 4 + r][nt * 16 + l16] = f2bf(acc[nt][r] + bias);
    }
    asm volatile("s_waitcnt lgkmcnt(0)" ::: "memory");   // same-wave ds order

    if (which < 2) {
        unsigned short* outp = (which == 0) ? qh : kh;
        const int r2 = lane >> 2;          // 0..15
        const int c2 = (lane & 3) << 4;    // {0,16,32,48}
        unsigned short* og = outp + (size_t)(m0 + wv * 16 + r2) * DH + c2;
        *(int4*)og       = *(const int4*)&ot[wv][r2][c2];
        *(int4*)(og + 8) = *(const int4*)&ot[wv][r2][c2 + 8];
    } else {
        // vhT[b][h][s]: lane owns column h=lane, s-range [s0, s0+16)
        const int bb = m0 >> 12;
        const int s0 = (m0 & 4095) + wv * 16;
        __align__(16) unsigned short tmp[16];
#pragma unroll
        for (int i = 0; i < 16; ++i) tmp[i] = ot[wv][i][lane];
        unsigned short* og = vhT + (size_t)bb * DH * SEQ + (size_t)lane * SEQ + s0;
        *(int4*)og       = *(const int4*)&tmp[0];
        *(int4*)(og + 8) = *(const int4*)&tmp[8];
    }
}

// ---------------------------------------------------------------------------
// Flash attention, causal, SPLIT-K over key chunks of 8 tiles (512 keys).
// (unchanged this round)
// ---------------------------------------------------------------------------
__global__ __launch_bounds__(256) void attn_split_kernel(
    const unsigned short* __restrict__ qh, const unsigned short* __restrict__ kh,
    const unsigned short* __restrict__ vhT,
    float* __restrict__ pO, float* __restrict__ pm, float* __restrict__ pl)
{
    const int chunk = blockIdx.x;
    const int qt    = blockIdx.y;
    const int b     = blockIdx.z;
    const int nc    = (qt + 8) >> 3;
    if (chunk >= nc) return;

    const int g = qt >> 3, rr = qt & 7;
    const int slot = b * SLOTS_PER_B + 4 * g * (g + 1) + rr * (g + 1) + chunk;
    const int c0 = chunk * 8;
    const int c1 = min(c0 + 8, qt + 1);

    __shared__ unsigned short k_t[64][72];
    __shared__ unsigned short v_t[64][72];
    __shared__ unsigned short qp[64][72];

    const int t    = threadIdx.x;
    const int wv   = t >> 6;
    const int lane = t & 63;
    const int quad = lane >> 4;
    const int l16  = lane & 15;
    const int sr   = t >> 2;
    const int sc   = (t & 3) << 4;

    const size_t base = (size_t)b * SEQ * DH;

    {   // stage Q tile
        const unsigned short* gq = qh + base + (size_t)(qt * 64 + sr) * DH + sc;
        *(int4*)&qp[sr][sc]     = *(const int4*)gq;
        *(int4*)&qp[sr][sc + 8] = *(const int4*)(gq + 8);
    }
    __syncthreads();
    bf16x8 qfrag[2];
    qfrag[0] = *(const bf16x8*)&qp[wv * 16 + l16][quad * 8];
    qfrag[1] = *(const bf16x8*)&qp[wv * 16 + l16][32 + quad * 8];

    f32x4 o_acc[4];
#pragma unroll
    for (int i = 0; i < 4; ++i) o_acc[i] = f32x4{0.f, 0.f, 0.f, 0.f};
    float m_i[4], l_i[4];
#pragma unroll
    for (int r = 0; r < 4; ++r) { m_i[r] = -1e30f; l_i[r] = 0.f; }

    const int rowb = wv * 16 + quad * 4;

    for (int jt = c0; jt < c1; ++jt) {
        __syncthreads();
        {
            const unsigned short* kg = kh + base + (size_t)(jt * 64 + sr) * DH + sc;
            *(int4*)&k_t[sr][sc]     = *(const int4*)kg;
            *(int4*)&k_t[sr][sc + 8] = *(const int4*)(kg + 8);
            const unsigned short* vg = vhT + (size_t)b * DH * SEQ + (size_t)sr * SEQ + (jt * 64 + sc);
            *(int4*)&v_t[sr][sc]     = *(const int4*)vg;
            *(int4*)&v_t[sr][sc + 8] = *(const int4*)(vg + 8);
        }
        __syncthreads();

        f32x4 s_acc[4];
#pragma unroll
        for (int i = 0; i < 4; ++i) s_acc[i] = f32x4{0.f, 0.f, 0.f, 0.f};
#pragma unroll
        for (int ks = 0; ks < 2; ++ks) {
#pragma unroll
            for (int nt = 0; nt < 4; ++nt) {
                bf16x8 bfr = *(const bf16x8*)&k_t[nt * 16 + l16][ks * 32 + quad * 8];
                s_acc[nt] = mfma_bf16(qfrag[ks], bfr, s_acc[nt]);
            }
        }

        const bool diag = (jt == qt);
#pragma unroll
        for (int nt = 0; nt < 4; ++nt) {
            const int col = nt * 16 + l16;
#pragma unroll
            for (int r = 0; r < 4; ++r) {
                float sv = s_acc[nt][r] * 0.125f;
                if (diag && (col > rowb + r)) sv = -1e30f;
                s_acc[nt][r] = sv;
            }
        }

        float mx[4];
#pragma unroll
        for (int r = 0; r < 4; ++r)
            mx[r] = fmaxf(fmaxf(s_acc[0][r], s_acc[1][r]), fmaxf(s_acc[2][r], s_acc[3][r]));
#pragma unroll
        for (int off = 1; off < 16; off <<= 1)
#pragma unroll
            for (int r = 0; r < 4; ++r)
                mx[r] = fmaxf(mx[r], __shfl_xor(mx[r], off, 64));

        float alpha[4];
#pragma unroll
        for (int r = 0; r < 4; ++r) {
            float mn = fmaxf(m_i[r], mx[r]);
            alpha[r] = __expf(m_i[r] - mn);
            m_i[r]   = mn;
        }

        float rs[4] = {0.f, 0.f, 0.f, 0.f};
#pragma unroll
        for (int nt = 0; nt < 4; ++nt)
#pragma unroll
            for (int r = 0; r < 4; ++r) {
                float p = __expf(s_acc[nt][r] - m_i[r]);
                s_acc[nt][r] = p;
                rs[r] += p;
            }
#pragma unroll
        for (int off = 1; off < 16; off <<= 1)
#pragma unroll
            for (int r = 0; r < 4; ++r)
                rs[r] += __shfl_xor(rs[r], off, 64);
#pragma unroll
        for (int r = 0; r < 4; ++r) l_i[r] = l_i[r] * alpha[r] + rs[r];

#pragma unroll
        for (int nt = 0; nt < 4; ++nt)
#pragma unroll
            for (int r = 0; r < 4; ++r)
                qp[rowb + r][nt * 16 + l16] = f2bf(s_acc[nt][r]);

#pragma unroll
        for (int nt = 0; nt < 4; ++nt)
#pragma unroll
            for (int r = 0; r < 4; ++r)
                o_acc[nt][r] *= alpha[r];

#pragma unroll
        for (int ks = 0; ks < 2; ++ks) {
            bf16x8 pa = *(const bf16x8*)&qp[wv * 16 + l16][ks * 32 + quad * 8];
#pragma unroll
            for (int nt = 0; nt < 4; ++nt) {
                bf16x8 vb = *(const bf16x8*)&v_t[nt * 16 + l16][ks * 32 + quad * 8];
                o_acc[nt] = mfma_bf16(pa, vb, o_acc[nt]);
            }
        }
    }

    // write unnormalized partials
    float* po = pO + (size_t)slot * 4096;
#pragma unroll
    for (int nt = 0; nt < 4; ++nt)
#pragma unroll
        for (int r = 0; r < 4; ++r)
            po[(rowb + r) * 64 + nt * 16 + l16] = o_acc[nt][r];
    if (l16 == 0) {
#pragma unroll
        for (int r = 0; r < 4; ++r) {
            pm[slot * 64 + rowb + r] = m_i[r];
            pl[slot * 64 + rowb + r] = l_i[r];
        }
    }
}

// ---------------------------------------------------------------------------
// Merge partials. Rows split 4-ways across blockIdx.z -> 1024 blocks
// (was 256 = 1 block/CU, latency-bound). Contiguous 256B pO reads per row.
// ---------------------------------------------------------------------------
__global__ __launch_bounds__(256) void attn_merge_kernel(
    const float* __restrict__ pO, const float* __restrict__ pm, const float* __restrict__ pl,
    float* __restrict__ out)
{
    const int qt = blockIdx.x;
    const int b  = blockIdx.y;
    const int rq = blockIdx.z;             // row quarter 0..3
    const int nc = (qt + 8) >> 3;
    const int g = qt >> 3, rr = qt & 7;
    const int s0 = b * SLOTS_PER_B + 4 * g * (g + 1) + rr * (g + 1);

    const int t   = threadIdx.x;
    const int row = rq * 16 + (t >> 4);    // 16 rows per block
    const int c0  = (t & 15) << 2;         // 16 chunks of 4 floats

    float mstar = -1e30f;
    for (int c = 0; c < nc; ++c)
        mstar = fmaxf(mstar, pm[(s0 + c) * 64 + row]);

    f32x4 acc = f32x4{0.f, 0.f, 0.f, 0.f};
    float lsum = 0.f;

    for (int c = 0; c < nc; ++c) {
        const float w = __expf(pm[(s0 + c) * 64 + row] - mstar);
        lsum += w * pl[(s0 + c) * 64 + row];
        f32x4 v = *(const f32x4*)(pO + (size_t)(s0 + c) * 4096 + row * 64 + c0);
        acc += w * v;
    }

    const float inv = 1.0f / lsum;
    float* og = out + (size_t)b * SEQ * DH + (size_t)(qt * 64 + row) * DH + c0;
    *(f32x4*)og = acc * inv;
}

extern "C" void kernel_launch(void* const* d_in, const int* in_sizes, int n_in,
                              void* d_out, int out_size, void* d_ws, size_t ws_size,
                              hipStream_t stream)
{
    (void)in_sizes; (void)n_in; (void)out_size; (void)ws_size;
    const float* q  = (const float*)d_in[0];
    const float* k  = (const float*)d_in[1];
    const float* v  = (const float*)d_in[2];
    const float* Wq = (const float*)d_in[3];
    const float* bq = (const float*)d_in[4];
    const float* Wk = (const float*)d_in[5];
    const float* bk = (const float*)d_in[6];
    const float* Wv = (const float*)d_in[7];
    const float* bv = (const float*)d_in[8];
    float* out = (float*)d_out;

    unsigned short* qh  = (unsigned short*)d_ws;
    unsigned short* kh  = qh + (size_t)NB * SEQ * DH;
    unsigned short* vhT = kh + (size_t)NB * SEQ * DH;
    float* pO = (float*)(vhT + (size_t)NB * SEQ * DH);
    float* pm = pO + (size_t)NB * SLOTS_PER_B * 4096;
    float* pl = pm + (size_t)NB * SLOTS_PER_B * 64;
    // Wfb aliases the START of pO: written by wprep, read by proj, then the
    // region is overwritten by attn_split's partials (stream-ordered, safe).
    unsigned short* Wfb = (unsigned short*)pO;

    wprep_kernel<<<dim3(16, 3), 256, 0, stream>>>(Wq, Wk, Wv, Wfb);
    proj_kernel<<<dim3(NB * SEQ / 64, 3), 256, 0, stream>>>(
        q, k, v, Wfb, bq, bk, bv, qh, kh, vhT);
    attn_split_kernel<<<dim3(8, SEQ / 64, NB), 256, 0, stream>>>(qh, kh, vhT, pO, pm, pl);
    attn_merge_kernel<<<dim3(SEQ / 64, NB, 4), 256, 0, stream>>>(pO, pm, pl, out);
}

// Round 4
// 282.751 us; speedup vs baseline: 1.0192x; 1.0192x over previous
//
#include <hip/hip_runtime.h>

#define SEQ 4096
#define DM  1024
#define DH  64
#define NB  4
#define SLOTS_PER_B 288   // sum_{qt=0}^{63} ceil((qt+1)/8)

typedef __attribute__((ext_vector_type(4))) float  f32x4;
typedef __attribute__((ext_vector_type(8))) __bf16 bf16x8;

__device__ __forceinline__ unsigned short f2bf(float f) {
    unsigned int u = __float_as_uint(f);
    u += 0x7FFFu + ((u >> 16) & 1u);          // RNE
    return (unsigned short)(u >> 16);
}

// native fptrunc -> compiler emits v_cvt_pk_bf16_f32 for pairs (RNE)
__device__ __forceinline__ unsigned short bfc(float f) {
    __bf16 h = (__bf16)f;
    return __builtin_bit_cast(unsigned short, h);
}

__device__ __forceinline__ bf16x8 cvt8(f32x4 lo, f32x4 hi) {
    bf16x8 r;
    r[0] = (__bf16)lo[0]; r[1] = (__bf16)lo[1]; r[2] = (__bf16)lo[2]; r[3] = (__bf16)lo[3];
    r[4] = (__bf16)hi[0]; r[5] = (__bf16)hi[1]; r[6] = (__bf16)hi[2]; r[7] = (__bf16)hi[3];
    return r;
}

__device__ __forceinline__ f32x4 mfma_bf16(bf16x8 a, bf16x8 b, f32x4 c) {
    return __builtin_amdgcn_mfma_f32_16x16x32_bf16(a, b, c, 0, 0, 0);
}

// ---------------------------------------------------------------------------
// W pre-convert: W[64][1024] fp32 -> bf16 in MFMA B-fragment order.
// Wf[which][kc(16)][ks(2)][nt(4)][lane(64)][8], elem = W[nt*16+l16][kc*64+ks*32+quad*8+j]
// ---------------------------------------------------------------------------
__global__ __launch_bounds__(256) void wprep_kernel(
    const float* __restrict__ Wq, const float* __restrict__ Wk, const float* __restrict__ Wv,
    unsigned short* __restrict__ Wf)
{
    const int which = blockIdx.y;
    const int kc    = blockIdx.x;                 // 0..15
    const float* W  = (which == 0) ? Wq : (which == 1) ? Wk : Wv;
    unsigned short* out = Wf + (size_t)which * 65536 + (size_t)kc * 4096;
    const int t = threadIdx.x;
#pragma unroll
    for (int s = t; s < 512; s += 256) {
        const int ks = s >> 8, nt = (s >> 6) & 3, ln = s & 63;
        const int qd = ln >> 4, l = ln & 15;
        const float* src = W + (size_t)(nt * 16 + l) * DM + kc * 64 + ks * 32 + qd * 8;
        f32x4 v0 = *(const f32x4*)src;
        f32x4 v1 = *(const f32x4*)(src + 4);
        *(ushort4*)(out + (size_t)s * 8)     = make_ushort4(bfc(v0[0]), bfc(v0[1]), bfc(v0[2]), bfc(v0[3]));
        *(ushort4*)(out + (size_t)s * 8 + 4) = make_ushort4(bfc(v1[0]), bfc(v1[1]), bfc(v1[2]), bfc(v1[3]));
    }
}

// ---------------------------------------------------------------------------
// Projection: Y = X[16384,1024] @ W[64,1024]^T + b  -> bf16
// K-SPLIT-4: block owns a 16-ROW tile; wave wv computes a partial over
// k in [wv*256, wv*256+256), then an LDS f32 reduction (+bias) merges.
// Grid 3072 blocks (12/CU). All 16 X f32x4 loads issued up front per wave
// (forces high-MLP regalloc). Waves barrier-free until the final reduce.
// ---------------------------------------------------------------------------
__global__ __launch_bounds__(256) void proj_kernel(
    const float* __restrict__ xq, const float* __restrict__ xk, const float* __restrict__ xv,
    const unsigned short* __restrict__ Wf,
    const float* __restrict__ bq, const float* __restrict__ bk, const float* __restrict__ bv,
    unsigned short* __restrict__ qh, unsigned short* __restrict__ kh,
    unsigned short* __restrict__ vhT)
{
    __shared__ float red[4][16][68];           // per-wave partial tiles (pad 68)
    __shared__ unsigned short ot[16][68];      // bf16 repack for vhT path

    const int which = blockIdx.y;
    const float* X  = (which == 0) ? xq : (which == 1) ? xk : xv;
    const float* Bb = (which == 0) ? bq : (which == 1) ? bk : bv;
    const unsigned short* Wg = Wf + (size_t)which * 65536;

    const int m0   = blockIdx.x * 16;          // 16-row tile
    const int t    = threadIdx.x;
    const int wv   = t >> 6;
    const int lane = t & 63;
    const int quad = lane >> 4;
    const int l16  = lane & 15;

    // A-frag: lane l16 = row, quad selects k-subrange; wave offset wv*256 in k
    const float* xrow = X + (size_t)(m0 + l16) * DM + wv * 256 + quad * 8;
    const unsigned short* wb = Wg + lane * 8;

    // ---- issue ALL X loads up front (16 independent f32x4, ~64 VGPR) ----
    f32x4 xa[16];
#pragma unroll
    for (int c = 0; c < 4; ++c) {
        xa[c * 4 + 0] = *(const f32x4*)(xrow + c * 64);
        xa[c * 4 + 1] = *(const f32x4*)(xrow + c * 64 + 4);
        xa[c * 4 + 2] = *(const f32x4*)(xrow + c * 64 + 32);
        xa[c * 4 + 3] = *(const f32x4*)(xrow + c * 64 + 36);
    }

    f32x4 acc[4];
#pragma unroll
    for (int i = 0; i < 4; ++i) acc[i] = f32x4{0.f, 0.f, 0.f, 0.f};

#pragma unroll
    for (int c = 0; c < 4; ++c) {
        const unsigned short* wc = wb + (size_t)(wv * 4 + c) * 4096;
        bf16x8 b0 = *(const bf16x8*)(wc);
        bf16x8 b1 = *(const bf16x8*)(wc + 512);
        bf16x8 b2 = *(const bf16x8*)(wc + 1024);
        bf16x8 b3 = *(const bf16x8*)(wc + 1536);
        bf16x8 b4 = *(const bf16x8*)(wc + 2048);
        bf16x8 b5 = *(const bf16x8*)(wc + 2560);
        bf16x8 b6 = *(const bf16x8*)(wc + 3072);
        bf16x8 b7 = *(const bf16x8*)(wc + 3584);

        bf16x8 a0 = cvt8(xa[c * 4 + 0], xa[c * 4 + 1]);   // ks=0
        bf16x8 a1 = cvt8(xa[c * 4 + 2], xa[c * 4 + 3]);   // ks=1

        acc[0] = mfma_bf16(a0, b0, acc[0]);
        acc[1] = mfma_bf16(a0, b1, acc[1]);
        acc[2] = mfma_bf16(a0, b2, acc[2]);
        acc[3] = mfma_bf16(a0, b3, acc[3]);
        acc[0] = mfma_bf16(a1, b4, acc[0]);
        acc[1] = mfma_bf16(a1, b5, acc[1]);
        acc[2] = mfma_bf16(a1, b6, acc[2]);
        acc[3] = mfma_bf16(a1, b7, acc[3]);
    }

    // ---- write per-wave partial to LDS (C-layout: row=quad*4+r, col=nt*16+l16) ----
#pragma unroll
    for (int nt = 0; nt < 4; ++nt)
#pragma unroll
        for (int r = 0; r < 4; ++r)
            red[wv][quad * 4 + r][nt * 16 + l16] = acc[nt][r];
    __syncthreads();

    // ---- cross-wave reduction + bias; thread t -> (row, 4 cols) ----
    const int row = t >> 4;           // 0..15
    const int c0  = (t & 15) << 2;    // 0,4,...,60
    f32x4 sum = *(const f32x4*)&red[0][row][c0];
    sum += *(const f32x4*)&red[1][row][c0];
    sum += *(const f32x4*)&red[2][row][c0];
    sum += *(const f32x4*)&red[3][row][c0];
    sum += *(const f32x4*)(Bb + c0);

    if (which < 2) {
        unsigned short* outp = (which == 0) ? qh : kh;
        unsigned short* og = outp + (size_t)(m0 + row) * DH + c0;
        *(ushort4*)og = make_ushort4(f2bf(sum[0]), f2bf(sum[1]), f2bf(sum[2]), f2bf(sum[3]));
    } else {
        // repack to vhT[b][h][s] via bf16 LDS tile
        ot[row][c0 + 0] = f2bf(sum[0]);
        ot[row][c0 + 1] = f2bf(sum[1]);
        ot[row][c0 + 2] = f2bf(sum[2]);
        ot[row][c0 + 3] = f2bf(sum[3]);
        __syncthreads();
        const int h  = t & 63;
        const int sq = t >> 6;        // 0..3, 4 s-values each
        ushort4 o = make_ushort4(ot[sq * 4 + 0][h], ot[sq * 4 + 1][h],
                                 ot[sq * 4 + 2][h], ot[sq * 4 + 3][h]);
        const int bb = m0 >> 12;
        const int s0 = (m0 & 4095) + sq * 4;
        unsigned short* og = vhT + (size_t)bb * DH * SEQ + (size_t)h * SEQ + s0;
        *(ushort4*)og = o;
    }
}

// ---------------------------------------------------------------------------
// Flash attention, causal, SPLIT-K over key chunks of 8 tiles (512 keys).
// (unchanged this round)
// ---------------------------------------------------------------------------
__global__ __launch_bounds__(256) void attn_split_kernel(
    const unsigned short* __restrict__ qh, const unsigned short* __restrict__ kh,
    const unsigned short* __restrict__ vhT,
    float* __restrict__ pO, float* __restrict__ pm, float* __restrict__ pl)
{
    const int chunk = blockIdx.x;
    const int qt    = blockIdx.y;
    const int b     = blockIdx.z;
    const int nc    = (qt + 8) >> 3;
    if (chunk >= nc) return;

    const int g = qt >> 3, rr = qt & 7;
    const int slot = b * SLOTS_PER_B + 4 * g * (g + 1) + rr * (g + 1) + chunk;
    const int c0 = chunk * 8;
    const int c1 = min(c0 + 8, qt + 1);

    __shared__ unsigned short k_t[64][72];
    __shared__ unsigned short v_t[64][72];
    __shared__ unsigned short qp[64][72];

    const int t    = threadIdx.x;
    const int wv   = t >> 6;
    const int lane = t & 63;
    const int quad = lane >> 4;
    const int l16  = lane & 15;
    const int sr   = t >> 2;
    const int sc   = (t & 3) << 4;

    const size_t base = (size_t)b * SEQ * DH;

    {   // stage Q tile
        const unsigned short* gq = qh + base + (size_t)(qt * 64 + sr) * DH + sc;
        *(int4*)&qp[sr][sc]     = *(const int4*)gq;
        *(int4*)&qp[sr][sc + 8] = *(const int4*)(gq + 8);
    }
    __syncthreads();
    bf16x8 qfrag[2];
    qfrag[0] = *(const bf16x8*)&qp[wv * 16 + l16][quad * 8];
    qfrag[1] = *(const bf16x8*)&qp[wv * 16 + l16][32 + quad * 8];

    f32x4 o_acc[4];
#pragma unroll
    for (int i = 0; i < 4; ++i) o_acc[i] = f32x4{0.f, 0.f, 0.f, 0.f};
    float m_i[4], l_i[4];
#pragma unroll
    for (int r = 0; r < 4; ++r) { m_i[r] = -1e30f; l_i[r] = 0.f; }

    const int rowb = wv * 16 + quad * 4;

    for (int jt = c0; jt < c1; ++jt) {
        __syncthreads();
        {
            const unsigned short* kg = kh + base + (size_t)(jt * 64 + sr) * DH + sc;
            *(int4*)&k_t[sr][sc]     = *(const int4*)kg;
            *(int4*)&k_t[sr][sc + 8] = *(const int4*)(kg + 8);
            const unsigned short* vg = vhT + (size_t)b * DH * SEQ + (size_t)sr * SEQ + (jt * 64 + sc);
            *(int4*)&v_t[sr][sc]     = *(const int4*)vg;
            *(int4*)&v_t[sr][sc + 8] = *(const int4*)(vg + 8);
        }
        __syncthreads();

        f32x4 s_acc[4];
#pragma unroll
        for (int i = 0; i < 4; ++i) s_acc[i] = f32x4{0.f, 0.f, 0.f, 0.f};
#pragma unroll
        for (int ks = 0; ks < 2; ++ks) {
#pragma unroll
            for (int nt = 0; nt < 4; ++nt) {
                bf16x8 bfr = *(const bf16x8*)&k_t[nt * 16 + l16][ks * 32 + quad * 8];
                s_acc[nt] = mfma_bf16(qfrag[ks], bfr, s_acc[nt]);
            }
        }

        const bool diag = (jt == qt);
#pragma unroll
        for (int nt = 0; nt < 4; ++nt) {
            const int col = nt * 16 + l16;
#pragma unroll
            for (int r = 0; r < 4; ++r) {
                float sv = s_acc[nt][r] * 0.125f;
                if (diag && (col > rowb + r)) sv = -1e30f;
                s_acc[nt][r] = sv;
            }
        }

        float mx[4];
#pragma unroll
        for (int r = 0; r < 4; ++r)
            mx[r] = fmaxf(fmaxf(s_acc[0][r], s_acc[1][r]), fmaxf(s_acc[2][r], s_acc[3][r]));
#pragma unroll
        for (int off = 1; off < 16; off <<= 1)
#pragma unroll
            for (int r = 0; r < 4; ++r)
                mx[r] = fmaxf(mx[r], __shfl_xor(mx[r], off, 64));

        float alpha[4];
#pragma unroll
        for (int r = 0; r < 4; ++r) {
            float mn = fmaxf(m_i[r], mx[r]);
            alpha[r] = __expf(m_i[r] - mn);
            m_i[r]   = mn;
        }

        float rs[4] = {0.f, 0.f, 0.f, 0.f};
#pragma unroll
        for (int nt = 0; nt < 4; ++nt)
#pragma unroll
            for (int r = 0; r < 4; ++r) {
                float p = __expf(s_acc[nt][r] - m_i[r]);
                s_acc[nt][r] = p;
                rs[r] += p;
            }
#pragma unroll
        for (int off = 1; off < 16; off <<= 1)
#pragma unroll
            for (int r = 0; r < 4; ++r)
                rs[r] += __shfl_xor(rs[r], off, 64);
#pragma unroll
        for (int r = 0; r < 4; ++r) l_i[r] = l_i[r] * alpha[r] + rs[r];

#pragma unroll
        for (int nt = 0; nt < 4; ++nt)
#pragma unroll
            for (int r = 0; r < 4; ++r)
                qp[rowb + r][nt * 16 + l16] = f2bf(s_acc[nt][r]);

#pragma unroll
        for (int nt = 0; nt < 4; ++nt)
#pragma unroll
            for (int r = 0; r < 4; ++r)
                o_acc[nt][r] *= alpha[r];

#pragma unroll
        for (int ks = 0; ks < 2; ++ks) {
            bf16x8 pa = *(const bf16x8*)&qp[wv * 16 + l16][ks * 32 + quad * 8];
#pragma unroll
            for (int nt = 0; nt < 4; ++nt) {
                bf16x8 vb = *(const bf16x8*)&v_t[nt * 16 + l16][ks * 32 + quad * 8];
                o_acc[nt] = mfma_bf16(pa, vb, o_acc[nt]);
            }
        }
    }

    // write unnormalized partials
    float* po = pO + (size_t)slot * 4096;
#pragma unroll
    for (int nt = 0; nt < 4; ++nt)
#pragma unroll
        for (int r = 0; r < 4; ++r)
            po[(rowb + r) * 64 + nt * 16 + l16] = o_acc[nt][r];
    if (l16 == 0) {
#pragma unroll
        for (int r = 0; r < 4; ++r) {
            pm[slot * 64 + rowb + r] = m_i[r];
            pl[slot * 64 + rowb + r] = l_i[r];
        }
    }
}

// ---------------------------------------------------------------------------
// Merge partials. Rows split 4-ways across blockIdx.z -> 1024 blocks.
// ---------------------------------------------------------------------------
__global__ __launch_bounds__(256) void attn_merge_kernel(
    const float* __restrict__ pO, const float* __restrict__ pm, const float* __restrict__ pl,
    float* __restrict__ out)
{
    const int qt = blockIdx.x;
    const int b  = blockIdx.y;
    const int rq = blockIdx.z;             // row quarter 0..3
    const int nc = (qt + 8) >> 3;
    const int g = qt >> 3, rr = qt & 7;
    const int s0 = b * SLOTS_PER_B + 4 * g * (g + 1) + rr * (g + 1);

    const int t   = threadIdx.x;
    const int row = rq * 16 + (t >> 4);    // 16 rows per block
    const int c0  = (t & 15) << 2;         // 16 chunks of 4 floats

    float mstar = -1e30f;
    for (int c = 0; c < nc; ++c)
        mstar = fmaxf(mstar, pm[(s0 + c) * 64 + row]);

    f32x4 acc = f32x4{0.f, 0.f, 0.f, 0.f};
    float lsum = 0.f;

    for (int c = 0; c < nc; ++c) {
        const float w = __expf(pm[(s0 + c) * 64 + row] - mstar);
        lsum += w * pl[(s0 + c) * 64 + row];
        f32x4 v = *(const f32x4*)(pO + (size_t)(s0 + c) * 4096 + row * 64 + c0);
        acc += w * v;
    }

    const float inv = 1.0f / lsum;
    float* og = out + (size_t)b * SEQ * DH + (size_t)(qt * 64 + row) * DH + c0;
    *(f32x4*)og = acc * inv;
}

extern "C" void kernel_launch(void* const* d_in, const int* in_sizes, int n_in,
                              void* d_out, int out_size, void* d_ws, size_t ws_size,
                              hipStream_t stream)
{
    (void)in_sizes; (void)n_in; (void)out_size; (void)ws_size;
    const float* q  = (const float*)d_in[0];
    const float* k  = (const float*)d_in[1];
    const float* v  = (const float*)d_in[2];
    const float* Wq = (const float*)d_in[3];
    const float* bq = (const float*)d_in[4];
    const float* Wk = (const float*)d_in[5];
    const float* bk = (const float*)d_in[6];
    const float* Wv = (const float*)d_in[7];
    const float* bv = (const float*)d_in[8];
    float* out = (float*)d_out;

    unsigned short* qh  = (unsigned short*)d_ws;
    unsigned short* kh  = qh + (size_t)NB * SEQ * DH;
    unsigned short* vhT = kh + (size_t)NB * SEQ * DH;
    float* pO = (float*)(vhT + (size_t)NB * SEQ * DH);
    float* pm = pO + (size_t)NB * SLOTS_PER_B * 4096;
    float* pl = pm + (size_t)NB * SLOTS_PER_B * 64;
    // Wfb aliases the START of pO: written by wprep, read by proj, then the
    // region is overwritten by attn_split's partials (stream-ordered, safe).
    unsigned short* Wfb = (unsigned short*)pO;

    wprep_kernel<<<dim3(16, 3), 256, 0, stream>>>(Wq, Wk, Wv, Wfb);
    proj_kernel<<<dim3(NB * SEQ / 16, 3), 256, 0, stream>>>(
        q, k, v, Wfb, bq, bk, bv, qh, kh, vhT);
    attn_split_kernel<<<dim3(8, SEQ / 64, NB), 256, 0, stream>>>(qh, kh, vhT, pO, pm, pl);
    attn_merge_kernel<<<dim3(SEQ / 64, NB, 4), 256, 0, stream>>>(pO, pm, pl, out);
}

// Round 5
// 279.440 us; speedup vs baseline: 1.0313x; 1.0119x over previous
//
#include <hip/hip_runtime.h>

#define SEQ 4096
#define DM  1024
#define DH  64
#define NB  4
#define SLOTS_PER_B 288   // sum_{qt=0}^{63} ceil((qt+1)/8)
#define XP  1032          // padded LDS row stride (bf16): 2-way bank alias on frag reads

typedef __attribute__((ext_vector_type(4))) float  f32x4;
typedef __attribute__((ext_vector_type(8))) __bf16 bf16x8;

__device__ __forceinline__ unsigned short f2bf(float f) {
    unsigned int u = __float_as_uint(f);
    u += 0x7FFFu + ((u >> 16) & 1u);          // RNE
    return (unsigned short)(u >> 16);
}

// native fptrunc -> compiler emits v_cvt_pk_bf16_f32 for pairs (RNE)
__device__ __forceinline__ unsigned short bfc(float f) {
    __bf16 h = (__bf16)f;
    return __builtin_bit_cast(unsigned short, h);
}

__device__ __forceinline__ f32x4 mfma_bf16(bf16x8 a, bf16x8 b, f32x4 c) {
    return __builtin_amdgcn_mfma_f32_16x16x32_bf16(a, b, c, 0, 0, 0);
}

// ---------------------------------------------------------------------------
// W pre-convert: W[64][1024] fp32 -> bf16 in MFMA B-fragment order.
// Wf[which][kc(16)][ks(2)][nt(4)][lane(64)][8], elem = W[nt*16+l16][kc*64+ks*32+quad*8+j]
// ---------------------------------------------------------------------------
__global__ __launch_bounds__(256) void wprep_kernel(
    const float* __restrict__ Wq, const float* __restrict__ Wk, const float* __restrict__ Wv,
    unsigned short* __restrict__ Wf)
{
    const int which = blockIdx.y;
    const int kc    = blockIdx.x;                 // 0..15
    const float* W  = (which == 0) ? Wq : (which == 1) ? Wk : Wv;
    unsigned short* out = Wf + (size_t)which * 65536 + (size_t)kc * 4096;
    const int t = threadIdx.x;
#pragma unroll
    for (int s = t; s < 512; s += 256) {
        const int ks = s >> 8, nt = (s >> 6) & 3, ln = s & 63;
        const int qd = ln >> 4, l = ln & 15;
        const float* src = W + (size_t)(nt * 16 + l) * DM + kc * 64 + ks * 32 + qd * 8;
        f32x4 v0 = *(const f32x4*)src;
        f32x4 v1 = *(const f32x4*)(src + 4);
        *(ushort4*)(out + (size_t)s * 8)     = make_ushort4(bfc(v0[0]), bfc(v0[1]), bfc(v0[2]), bfc(v0[3]));
        *(ushort4*)(out + (size_t)s * 8 + 4) = make_ushort4(bfc(v1[0]), bfc(v1[1]), bfc(v1[2]), bfc(v1[3]));
    }
}

// ---------------------------------------------------------------------------
// Projection: Y = X[16384,1024] @ W[64,1024]^T + b  -> bf16
// CONTIGUOUS-STREAM X staging: block = 16 rows; thread t, load j reads
// X[(m0+j)*1024 + t*4] -> every wave-load is 1 KB lane-contiguous, block
// reads a pure 64 KB stream (the one thing all prior 1.3 TB/s variants
// lacked). bf16-convert into LDS xt[16][XP]; K-split-4 MFMA compute per
// wave (verified round-4 structure); LDS f32 cross-wave reduce + bias.
// ---------------------------------------------------------------------------
__global__ __launch_bounds__(256) void proj_kernel(
    const float* __restrict__ xq, const float* __restrict__ xk, const float* __restrict__ xv,
    const unsigned short* __restrict__ Wf,
    const float* __restrict__ bq, const float* __restrict__ bk, const float* __restrict__ bv,
    unsigned short* __restrict__ qh, unsigned short* __restrict__ kh,
    unsigned short* __restrict__ vhT)
{
    // xt (33 KB) is live until the last frag read; red/ot reuse its space after.
    __shared__ __align__(16) char smem[16 * XP * 2];                    // 33024 B
    unsigned short (*xt)[XP]  = (unsigned short(*)[XP])smem;
    float (*red)[16][68]      = (float(*)[16][68])smem;                 // 17408 B
    unsigned short (*ot)[68]  = (unsigned short(*)[68])(smem + 17408);  // 2176 B

    const int which = blockIdx.y;
    const float* X  = (which == 0) ? xq : (which == 1) ? xk : xv;
    const float* Bb = (which == 0) ? bq : (which == 1) ? bk : bv;
    const unsigned short* Wg = Wf + (size_t)which * 65536;

    const int m0   = blockIdx.x * 16;          // 16-row tile
    const int t    = threadIdx.x;
    const int wv   = t >> 6;
    const int lane = t & 63;
    const int quad = lane >> 4;
    const int l16  = lane & 15;

    // ---- stage X: 16 lane-contiguous 1KB wave-loads (64 KB stream/block) ----
    const float* xbase = X + (size_t)m0 * DM + t * 4;
    f32x4 xr[16];
#pragma unroll
    for (int j = 0; j < 16; ++j)
        xr[j] = *(const f32x4*)(xbase + j * DM);
    __builtin_amdgcn_sched_barrier(0);   // pin: all 16 loads issued (MLP=16)
#pragma unroll
    for (int j = 0; j < 16; ++j)
        *(ushort4*)&xt[j][t * 4] =
            make_ushort4(bfc(xr[j][0]), bfc(xr[j][1]), bfc(xr[j][2]), bfc(xr[j][3]));
    __syncthreads();

    // ---- K-split-4 compute: wave wv covers k in [wv*256, wv*256+256) ----
    const unsigned short* wb = Wg + lane * 8;
    f32x4 acc[4];
#pragma unroll
    for (int i = 0; i < 4; ++i) acc[i] = f32x4{0.f, 0.f, 0.f, 0.f};

#pragma unroll
    for (int c = 0; c < 4; ++c) {
        const int k0 = wv * 256 + c * 64;
        const unsigned short* wc = wb + (size_t)(wv * 4 + c) * 4096;
        bf16x8 b0 = *(const bf16x8*)(wc);
        bf16x8 b1 = *(const bf16x8*)(wc + 512);
        bf16x8 b2 = *(const bf16x8*)(wc + 1024);
        bf16x8 b3 = *(const bf16x8*)(wc + 1536);
        bf16x8 b4 = *(const bf16x8*)(wc + 2048);
        bf16x8 b5 = *(const bf16x8*)(wc + 2560);
        bf16x8 b6 = *(const bf16x8*)(wc + 3072);
        bf16x8 b7 = *(const bf16x8*)(wc + 3584);

        bf16x8 a0 = *(const bf16x8*)&xt[l16][k0 + quad * 8];        // ks=0
        bf16x8 a1 = *(const bf16x8*)&xt[l16][k0 + 32 + quad * 8];   // ks=1

        acc[0] = mfma_bf16(a0, b0, acc[0]);
        acc[1] = mfma_bf16(a0, b1, acc[1]);
        acc[2] = mfma_bf16(a0, b2, acc[2]);
        acc[3] = mfma_bf16(a0, b3, acc[3]);
        acc[0] = mfma_bf16(a1, b4, acc[0]);
        acc[1] = mfma_bf16(a1, b5, acc[1]);
        acc[2] = mfma_bf16(a1, b6, acc[2]);
        acc[3] = mfma_bf16(a1, b7, acc[3]);
    }
    __syncthreads();   // all xt reads done; safe to reuse smem as red/ot

    // ---- per-wave partial -> LDS (C-layout: row=quad*4+r, col=nt*16+l16) ----
#pragma unroll
    for (int nt = 0; nt < 4; ++nt)
#pragma unroll
        for (int r = 0; r < 4; ++r)
            red[wv][quad * 4 + r][nt * 16 + l16] = acc[nt][r];
    __syncthreads();

    // ---- cross-wave reduction + bias; thread t -> (row, 4 cols) ----
    const int row = t >> 4;           // 0..15
    const int c0  = (t & 15) << 2;    // 0,4,...,60
    f32x4 sum = *(const f32x4*)&red[0][row][c0];
    sum += *(const f32x4*)&red[1][row][c0];
    sum += *(const f32x4*)&red[2][row][c0];
    sum += *(const f32x4*)&red[3][row][c0];
    sum += *(const f32x4*)(Bb + c0);

    if (which < 2) {
        unsigned short* outp = (which == 0) ? qh : kh;
        unsigned short* og = outp + (size_t)(m0 + row) * DH + c0;
        *(ushort4*)og = make_ushort4(f2bf(sum[0]), f2bf(sum[1]), f2bf(sum[2]), f2bf(sum[3]));
    } else {
        // repack to vhT[b][h][s] via bf16 LDS tile
        ot[row][c0 + 0] = f2bf(sum[0]);
        ot[row][c0 + 1] = f2bf(sum[1]);
        ot[row][c0 + 2] = f2bf(sum[2]);
        ot[row][c0 + 3] = f2bf(sum[3]);
        __syncthreads();
        const int h  = t & 63;
        const int sq = t >> 6;        // 0..3, 4 s-values each
        ushort4 o = make_ushort4(ot[sq * 4 + 0][h], ot[sq * 4 + 1][h],
                                 ot[sq * 4 + 2][h], ot[sq * 4 + 3][h]);
        const int bb = m0 >> 12;
        const int s0 = (m0 & 4095) + sq * 4;
        unsigned short* og = vhT + (size_t)bb * DH * SEQ + (size_t)h * SEQ + s0;
        *(ushort4*)og = o;
    }
}

// ---------------------------------------------------------------------------
// Flash attention, causal, SPLIT-K over key chunks of 8 tiles (512 keys).
// (unchanged this round — will surface in top-5 once proj shrinks)
// ---------------------------------------------------------------------------
__global__ __launch_bounds__(256) void attn_split_kernel(
    const unsigned short* __restrict__ qh, const unsigned short* __restrict__ kh,
    const unsigned short* __restrict__ vhT,
    float* __restrict__ pO, float* __restrict__ pm, float* __restrict__ pl)
{
    const int chunk = blockIdx.x;
    const int qt    = blockIdx.y;
    const int b     = blockIdx.z;
    const int nc    = (qt + 8) >> 3;
    if (chunk >= nc) return;

    const int g = qt >> 3, rr = qt & 7;
    const int slot = b * SLOTS_PER_B + 4 * g * (g + 1) + rr * (g + 1) + chunk;
    const int c0 = chunk * 8;
    const int c1 = min(c0 + 8, qt + 1);

    __shared__ unsigned short k_t[64][72];
    __shared__ unsigned short v_t[64][72];
    __shared__ unsigned short qp[64][72];

    const int t    = threadIdx.x;
    const int wv   = t >> 6;
    const int lane = t & 63;
    const int quad = lane >> 4;
    const int l16  = lane & 15;
    const int sr   = t >> 2;
    const int sc   = (t & 3) << 4;

    const size_t base = (size_t)b * SEQ * DH;

    {   // stage Q tile
        const unsigned short* gq = qh + base + (size_t)(qt * 64 + sr) * DH + sc;
        *(int4*)&qp[sr][sc]     = *(const int4*)gq;
        *(int4*)&qp[sr][sc + 8] = *(const int4*)(gq + 8);
    }
    __syncthreads();
    bf16x8 qfrag[2];
    qfrag[0] = *(const bf16x8*)&qp[wv * 16 + l16][quad * 8];
    qfrag[1] = *(const bf16x8*)&qp[wv * 16 + l16][32 + quad * 8];

    f32x4 o_acc[4];
#pragma unroll
    for (int i = 0; i < 4; ++i) o_acc[i] = f32x4{0.f, 0.f, 0.f, 0.f};
    float m_i[4], l_i[4];
#pragma unroll
    for (int r = 0; r < 4; ++r) { m_i[r] = -1e30f; l_i[r] = 0.f; }

    const int rowb = wv * 16 + quad * 4;

    for (int jt = c0; jt < c1; ++jt) {
        __syncthreads();
        {
            const unsigned short* kg = kh + base + (size_t)(jt * 64 + sr) * DH + sc;
            *(int4*)&k_t[sr][sc]     = *(const int4*)kg;
            *(int4*)&k_t[sr][sc + 8] = *(const int4*)(kg + 8);
            const unsigned short* vg = vhT + (size_t)b * DH * SEQ + (size_t)sr * SEQ + (jt * 64 + sc);
            *(int4*)&v_t[sr][sc]     = *(const int4*)vg;
            *(int4*)&v_t[sr][sc + 8] = *(const int4*)(vg + 8);
        }
        __syncthreads();

        f32x4 s_acc[4];
#pragma unroll
        for (int i = 0; i < 4; ++i) s_acc[i] = f32x4{0.f, 0.f, 0.f, 0.f};
#pragma unroll
        for (int ks = 0; ks < 2; ++ks) {
#pragma unroll
            for (int nt = 0; nt < 4; ++nt) {
                bf16x8 bfr = *(const bf16x8*)&k_t[nt * 16 + l16][ks * 32 + quad * 8];
                s_acc[nt] = mfma_bf16(qfrag[ks], bfr, s_acc[nt]);
            }
        }

        const bool diag = (jt == qt);
#pragma unroll
        for (int nt = 0; nt < 4; ++nt) {
            const int col = nt * 16 + l16;
#pragma unroll
            for (int r = 0; r < 4; ++r) {
                float sv = s_acc[nt][r] * 0.125f;
                if (diag && (col > rowb + r)) sv = -1e30f;
                s_acc[nt][r] = sv;
            }
        }

        float mx[4];
#pragma unroll
        for (int r = 0; r < 4; ++r)
            mx[r] = fmaxf(fmaxf(s_acc[0][r], s_acc[1][r]), fmaxf(s_acc[2][r], s_acc[3][r]));
#pragma unroll
        for (int off = 1; off < 16; off <<= 1)
#pragma unroll
            for (int r = 0; r < 4; ++r)
                mx[r] = fmaxf(mx[r], __shfl_xor(mx[r], off, 64));

        float alpha[4];
#pragma unroll
        for (int r = 0; r < 4; ++r) {
            float mn = fmaxf(m_i[r], mx[r]);
            alpha[r] = __expf(m_i[r] - mn);
            m_i[r]   = mn;
        }

        float rs[4] = {0.f, 0.f, 0.f, 0.f};
#pragma unroll
        for (int nt = 0; nt < 4; ++nt)
#pragma unroll
            for (int r = 0; r < 4; ++r) {
                float p = __expf(s_acc[nt][r] - m_i[r]);
                s_acc[nt][r] = p;
                rs[r] += p;
            }
#pragma unroll
        for (int off = 1; off < 16; off <<= 1)
#pragma unroll
            for (int r = 0; r < 4; ++r)
                rs[r] += __shfl_xor(rs[r], off, 64);
#pragma unroll
        for (int r = 0; r < 4; ++r) l_i[r] = l_i[r] * alpha[r] + rs[r];

#pragma unroll
        for (int nt = 0; nt < 4; ++nt)
#pragma unroll
            for (int r = 0; r < 4; ++r)
                qp[rowb + r][nt * 16 + l16] = f2bf(s_acc[nt][r]);

#pragma unroll
        for (int nt = 0; nt < 4; ++nt)
#pragma unroll
            for (int r = 0; r < 4; ++r)
                o_acc[nt][r] *= alpha[r];

#pragma unroll
        for (int ks = 0; ks < 2; ++ks) {
            bf16x8 pa = *(const bf16x8*)&qp[wv * 16 + l16][ks * 32 + quad * 8];
#pragma unroll
            for (int nt = 0; nt < 4; ++nt) {
                bf16x8 vb = *(const bf16x8*)&v_t[nt * 16 + l16][ks * 32 + quad * 8];
                o_acc[nt] = mfma_bf16(pa, vb, o_acc[nt]);
            }
        }
    }

    // write unnormalized partials
    float* po = pO + (size_t)slot * 4096;
#pragma unroll
    for (int nt = 0; nt < 4; ++nt)
#pragma unroll
        for (int r = 0; r < 4; ++r)
            po[(rowb + r) * 64 + nt * 16 + l16] = o_acc[nt][r];
    if (l16 == 0) {
#pragma unroll
        for (int r = 0; r < 4; ++r) {
            pm[slot * 64 + rowb + r] = m_i[r];
            pl[slot * 64 + rowb + r] = l_i[r];
        }
    }
}

// ---------------------------------------------------------------------------
// Merge partials. Rows split 4-ways across blockIdx.z -> 1024 blocks.
// ---------------------------------------------------------------------------
__global__ __launch_bounds__(256) void attn_merge_kernel(
    const float* __restrict__ pO, const float* __restrict__ pm, const float* __restrict__ pl,
    float* __restrict__ out)
{
    const int qt = blockIdx.x;
    const int b  = blockIdx.y;
    const int rq = blockIdx.z;             // row quarter 0..3
    const int nc = (qt + 8) >> 3;
    const int g = qt >> 3, rr = qt & 7;
    const int s0 = b * SLOTS_PER_B + 4 * g * (g + 1) + rr * (g + 1);

    const int t   = threadIdx.x;
    const int row = rq * 16 + (t >> 4);    // 16 rows per block
    const int c0  = (t & 15) << 2;         // 16 chunks of 4 floats

    float mstar = -1e30f;
    for (int c = 0; c < nc; ++c)
        mstar = fmaxf(mstar, pm[(s0 + c) * 64 + row]);

    f32x4 acc = f32x4{0.f, 0.f, 0.f, 0.f};
    float lsum = 0.f;

    for (int c = 0; c < nc; ++c) {
        const float w = __expf(pm[(s0 + c) * 64 + row] - mstar);
        lsum += w * pl[(s0 + c) * 64 + row];
        f32x4 v = *(const f32x4*)(pO + (size_t)(s0 + c) * 4096 + row * 64 + c0);
        acc += w * v;
    }

    const float inv = 1.0f / lsum;
    float* og = out + (size_t)b * SEQ * DH + (size_t)(qt * 64 + row) * DH + c0;
    *(f32x4*)og = acc * inv;
}

extern "C" void kernel_launch(void* const* d_in, const int* in_sizes, int n_in,
                              void* d_out, int out_size, void* d_ws, size_t ws_size,
                              hipStream_t stream)
{
    (void)in_sizes; (void)n_in; (void)out_size; (void)ws_size;
    const float* q  = (const float*)d_in[0];
    const float* k  = (const float*)d_in[1];
    const float* v  = (const float*)d_in[2];
    const float* Wq = (const float*)d_in[3];
    const float* bq = (const float*)d_in[4];
    const float* Wk = (const float*)d_in[5];
    const float* bk = (const float*)d_in[6];
    const float* Wv = (const float*)d_in[7];
    const float* bv = (const float*)d_in[8];
    float* out = (float*)d_out;

    unsigned short* qh  = (unsigned short*)d_ws;
    unsigned short* kh  = qh + (size_t)NB * SEQ * DH;
    unsigned short* vhT = kh + (size_t)NB * SEQ * DH;
    float* pO = (float*)(vhT + (size_t)NB * SEQ * DH);
    float* pm = pO + (size_t)NB * SLOTS_PER_B * 4096;
    float* pl = pm + (size_t)NB * SLOTS_PER_B * 64;
    // Wfb aliases the START of pO: written by wprep, read by proj, then the
    // region is overwritten by attn_split's partials (stream-ordered, safe).
    unsigned short* Wfb = (unsigned short*)pO;

    wprep_kernel<<<dim3(16, 3), 256, 0, stream>>>(Wq, Wk, Wv, Wfb);
    proj_kernel<<<dim3(NB * SEQ / 16, 3), 256, 0, stream>>>(
        q, k, v, Wfb, bq, bk, bv, qh, kh, vhT);
    attn_split_kernel<<<dim3(8, SEQ / 64, NB), 256, 0, stream>>>(qh, kh, vhT, pO, pm, pl);
    attn_merge_kernel<<<dim3(SEQ / 64, NB, 4), 256, 0, stream>>>(pO, pm, pl, out);
}

// Round 8
// 278.204 us; speedup vs baseline: 1.0358x; 1.0044x over previous
//
#include <hip/hip_runtime.h>

#define SEQ 4096
#define DM  1024
#define DH  64
#define NB  4
#define SLOTS_PER_B 288   // sum_{qt=0}^{63} ceil((qt+1)/8)
#define XP  1032          // padded LDS row stride (bf16)

typedef __attribute__((ext_vector_type(4))) float  f32x4;
typedef __attribute__((ext_vector_type(8))) __bf16 bf16x8;

__device__ __forceinline__ unsigned short f2bf(float f) {
    unsigned int u = __float_as_uint(f);
    u += 0x7FFFu + ((u >> 16) & 1u);          // RNE
    return (unsigned short)(u >> 16);
}

__device__ __forceinline__ unsigned short bfc(float f) {
    __bf16 h = (__bf16)f;
    return __builtin_bit_cast(unsigned short, h);
}

__device__ __forceinline__ f32x4 mfma_bf16(bf16x8 a, bf16x8 b, f32x4 c) {
    return __builtin_amdgcn_mfma_f32_16x16x32_bf16(a, b, c, 0, 0, 0);
}

// ---------------------------------------------------------------------------
// W pre-convert: W[64][1024] fp32 -> bf16 in MFMA B-fragment order.
// Wf[which][kc(16)][ks(2)][nt(4)][lane(64)][8], elem = W[nt*16+l16][kc*64+ks*32+quad*8+j]
// ---------------------------------------------------------------------------
__global__ __launch_bounds__(256) void wprep_kernel(
    const float* __restrict__ Wq, const float* __restrict__ Wk, const float* __restrict__ Wv,
    unsigned short* __restrict__ Wf)
{
    const int which = blockIdx.y;
    const int kc    = blockIdx.x;                 // 0..15
    const float* W  = (which == 0) ? Wq : (which == 1) ? Wk : Wv;
    unsigned short* out = Wf + (size_t)which * 65536 + (size_t)kc * 4096;
    const int t = threadIdx.x;
#pragma unroll
    for (int s = t; s < 512; s += 256) {
        const int ks = s >> 8, nt = (s >> 6) & 3, ln = s & 63;
        const int qd = ln >> 4, l = ln & 15;
        const float* src = W + (size_t)(nt * 16 + l) * DM + kc * 64 + ks * 32 + qd * 8;
        f32x4 v0 = *(const f32x4*)src;
        f32x4 v1 = *(const f32x4*)(src + 4);
        *(ushort4*)(out + (size_t)s * 8)     = make_ushort4(bfc(v0[0]), bfc(v0[1]), bfc(v0[2]), bfc(v0[3]));
        *(ushort4*)(out + (size_t)s * 8 + 4) = make_ushort4(bfc(v1[0]), bfc(v1[1]), bfc(v1[2]), bfc(v1[3]));
    }
}

// ---------------------------------------------------------------------------
// Projection: Y = X[16384,1024] @ W[64,1024]^T + b  -> bf16
// Round-5 passing body, ONE delta: __launch_bounds__(256,2) lifts the VGPR
// cap 64 -> 256 so the scheduler can keep the 16 X f32x4 loads in flight
// (round 5's VGPR_Count=52 proves they were serialized: 16 live loads need
// 64 VGPRs). Readout: VGPR_Count >= ~85 means the hoist happened.
// ---------------------------------------------------------------------------
__global__ __launch_bounds__(256, 2) void proj_kernel(
    const float* __restrict__ xq, const float* __restrict__ xk, const float* __restrict__ xv,
    const unsigned short* __restrict__ Wf,
    const float* __restrict__ bq, const float* __restrict__ bk, const float* __restrict__ bv,
    unsigned short* __restrict__ qh, unsigned short* __restrict__ kh,
    unsigned short* __restrict__ vhT)
{
    __shared__ __align__(16) char smem[16 * XP * 2];                    // 33024 B
    unsigned short (*xt)[XP]  = (unsigned short(*)[XP])smem;
    float (*red)[16][68]      = (float(*)[16][68])smem;                 // 17408 B
    unsigned short (*ot)[68]  = (unsigned short(*)[68])(smem + 17408);  // 2176 B

    const int which = blockIdx.y;
    const float* X  = (which == 0) ? xq : (which == 1) ? xk : xv;
    const float* Bb = (which == 0) ? bq : (which == 1) ? bk : bv;
    const unsigned short* Wg = Wf + (size_t)which * 65536;

    const int m0   = blockIdx.x * 16;          // 16-row tile
    const int t    = threadIdx.x;
    const int wv   = t >> 6;
    const int lane = t & 63;
    const int quad = lane >> 4;
    const int l16  = lane & 15;

    // ---- stage X: 16 lane-contiguous 1KB wave-loads (64 KB stream/block) ----
    const float* xbase = X + (size_t)m0 * DM + t * 4;
    f32x4 xr[16];
#pragma unroll
    for (int j = 0; j < 16; ++j)
        xr[j] = *(const f32x4*)(xbase + j * DM);
    __builtin_amdgcn_sched_barrier(0);   // region boundary: loads above, converts below
#pragma unroll
    for (int j = 0; j < 16; ++j)
        *(ushort4*)&xt[j][t * 4] =
            make_ushort4(bfc(xr[j][0]), bfc(xr[j][1]), bfc(xr[j][2]), bfc(xr[j][3]));
    __syncthreads();

    // ---- K-split-4 compute: wave wv covers k in [wv*256, wv*256+256) ----
    const unsigned short* wb = Wg + lane * 8;
    f32x4 acc[4];
#pragma unroll
    for (int i = 0; i < 4; ++i) acc[i] = f32x4{0.f, 0.f, 0.f, 0.f};

#pragma unroll
    for (int c = 0; c < 4; ++c) {
        const int k0 = wv * 256 + c * 64;
        const unsigned short* wc = wb + (size_t)(wv * 4 + c) * 4096;
        bf16x8 b0 = *(const bf16x8*)(wc);
        bf16x8 b1 = *(const bf16x8*)(wc + 512);
        bf16x8 b2 = *(const bf16x8*)(wc + 1024);
        bf16x8 b3 = *(const bf16x8*)(wc + 1536);
        bf16x8 b4 = *(const bf16x8*)(wc + 2048);
        bf16x8 b5 = *(const bf16x8*)(wc + 2560);
        bf16x8 b6 = *(const bf16x8*)(wc + 3072);
        bf16x8 b7 = *(const bf16x8*)(wc + 3584);

        bf16x8 a0 = *(const bf16x8*)&xt[l16][k0 + quad * 8];        // ks=0
        bf16x8 a1 = *(const bf16x8*)&xt[l16][k0 + 32 + quad * 8];   // ks=1

        acc[0] = mfma_bf16(a0, b0, acc[0]);
        acc[1] = mfma_bf16(a0, b1, acc[1]);
        acc[2] = mfma_bf16(a0, b2, acc[2]);
        acc[3] = mfma_bf16(a0, b3, acc[3]);
        acc[0] = mfma_bf16(a1, b4, acc[0]);
        acc[1] = mfma_bf16(a1, b5, acc[1]);
        acc[2] = mfma_bf16(a1, b6, acc[2]);
        acc[3] = mfma_bf16(a1, b7, acc[3]);
    }
    __syncthreads();   // all xt reads done; reuse smem as red/ot

    // ---- per-wave partial -> LDS ----
#pragma unroll
    for (int nt = 0; nt < 4; ++nt)
#pragma unroll
        for (int r = 0; r < 4; ++r)
            red[wv][quad * 4 + r][nt * 16 + l16] = acc[nt][r];
    __syncthreads();

    // ---- cross-wave reduction + bias ----
    const int row = t >> 4;           // 0..15
    const int c0  = (t & 15) << 2;    // 0,4,...,60
    f32x4 sum = *(const f32x4*)&red[0][row][c0];
    sum += *(const f32x4*)&red[1][row][c0];
    sum += *(const f32x4*)&red[2][row][c0];
    sum += *(const f32x4*)&red[3][row][c0];
    sum += *(const f32x4*)(Bb + c0);

    if (which < 2) {
        unsigned short* outp = (which == 0) ? qh : kh;
        unsigned short* og = outp + (size_t)(m0 + row) * DH + c0;
        *(ushort4*)og = make_ushort4(f2bf(sum[0]), f2bf(sum[1]), f2bf(sum[2]), f2bf(sum[3]));
    } else {
        ot[row][c0 + 0] = f2bf(sum[0]);
        ot[row][c0 + 1] = f2bf(sum[1]);
        ot[row][c0 + 2] = f2bf(sum[2]);
        ot[row][c0 + 3] = f2bf(sum[3]);
        __syncthreads();
        const int h  = t & 63;
        const int sq = t >> 6;        // 0..3, 4 s-values each
        ushort4 o = make_ushort4(ot[sq * 4 + 0][h], ot[sq * 4 + 1][h],
                                 ot[sq * 4 + 2][h], ot[sq * 4 + 3][h]);
        const int bb = m0 >> 12;
        const int s0 = (m0 & 4095) + sq * 4;
        unsigned short* og = vhT + (size_t)bb * DH * SEQ + (size_t)h * SEQ + s0;
        *(ushort4*)og = o;
    }
}

// ---------------------------------------------------------------------------
// Flash attention, causal, SPLIT-K over key chunks of 8 tiles (512 keys).
// Byte-identical to the round-5 PASSING version.
// ---------------------------------------------------------------------------
__global__ __launch_bounds__(256) void attn_split_kernel(
    const unsigned short* __restrict__ qh, const unsigned short* __restrict__ kh,
    const unsigned short* __restrict__ vhT,
    float* __restrict__ pO, float* __restrict__ pm, float* __restrict__ pl)
{
    const int chunk = blockIdx.x;
    const int qt    = blockIdx.y;
    const int b     = blockIdx.z;
    const int nc    = (qt + 8) >> 3;
    if (chunk >= nc) return;

    const int g = qt >> 3, rr = qt & 7;
    const int slot = b * SLOTS_PER_B + 4 * g * (g + 1) + rr * (g + 1) + chunk;
    const int c0 = chunk * 8;
    const int c1 = min(c0 + 8, qt + 1);

    __shared__ unsigned short k_t[64][72];
    __shared__ unsigned short v_t[64][72];
    __shared__ unsigned short qp[64][72];

    const int t    = threadIdx.x;
    const int wv   = t >> 6;
    const int lane = t & 63;
    const int quad = lane >> 4;
    const int l16  = lane & 15;
    const int sr   = t >> 2;
    const int sc   = (t & 3) << 4;

    const size_t base = (size_t)b * SEQ * DH;

    {   // stage Q tile
        const unsigned short* gq = qh + base + (size_t)(qt * 64 + sr) * DH + sc;
        *(int4*)&qp[sr][sc]     = *(const int4*)gq;
        *(int4*)&qp[sr][sc + 8] = *(const int4*)(gq + 8);
    }
    __syncthreads();
    bf16x8 qfrag[2];
    qfrag[0] = *(const bf16x8*)&qp[wv * 16 + l16][quad * 8];
    qfrag[1] = *(const bf16x8*)&qp[wv * 16 + l16][32 + quad * 8];

    f32x4 o_acc[4];
#pragma unroll
    for (int i = 0; i < 4; ++i) o_acc[i] = f32x4{0.f, 0.f, 0.f, 0.f};
    float m_i[4], l_i[4];
#pragma unroll
    for (int r = 0; r < 4; ++r) { m_i[r] = -1e30f; l_i[r] = 0.f; }

    const int rowb = wv * 16 + quad * 4;

    for (int jt = c0; jt < c1; ++jt) {
        __syncthreads();
        {
            const unsigned short* kg = kh + base + (size_t)(jt * 64 + sr) * DH + sc;
            *(int4*)&k_t[sr][sc]     = *(const int4*)kg;
            *(int4*)&k_t[sr][sc + 8] = *(const int4*)(kg + 8);
            const unsigned short* vg = vhT + (size_t)b * DH * SEQ + (size_t)sr * SEQ + (jt * 64 + sc);
            *(int4*)&v_t[sr][sc]     = *(const int4*)vg;
            *(int4*)&v_t[sr][sc + 8] = *(const int4*)(vg + 8);
        }
        __syncthreads();

        f32x4 s_acc[4];
#pragma unroll
        for (int i = 0; i < 4; ++i) s_acc[i] = f32x4{0.f, 0.f, 0.f, 0.f};
#pragma unroll
        for (int ks = 0; ks < 2; ++ks) {
#pragma unroll
            for (int nt = 0; nt < 4; ++nt) {
                bf16x8 bfr = *(const bf16x8*)&k_t[nt * 16 + l16][ks * 32 + quad * 8];
                s_acc[nt] = mfma_bf16(qfrag[ks], bfr, s_acc[nt]);
            }
        }

        const bool diag = (jt == qt);
#pragma unroll
        for (int nt = 0; nt < 4; ++nt) {
            const int col = nt * 16 + l16;
#pragma unroll
            for (int r = 0; r < 4; ++r) {
                float sv = s_acc[nt][r] * 0.125f;
                if (diag && (col > rowb + r)) sv = -1e30f;
                s_acc[nt][r] = sv;
            }
        }

        float mx[4];
#pragma unroll
        for (int r = 0; r < 4; ++r)
            mx[r] = fmaxf(fmaxf(s_acc[0][r], s_acc[1][r]), fmaxf(s_acc[2][r], s_acc[3][r]));
#pragma unroll
        for (int off = 1; off < 16; off <<= 1)
#pragma unroll
            for (int r = 0; r < 4; ++r)
                mx[r] = fmaxf(mx[r], __shfl_xor(mx[r], off, 64));

        float alpha[4];
#pragma unroll
        for (int r = 0; r < 4; ++r) {
            float mn = fmaxf(m_i[r], mx[r]);
            alpha[r] = __expf(m_i[r] - mn);
            m_i[r]   = mn;
        }

        float rs[4] = {0.f, 0.f, 0.f, 0.f};
#pragma unroll
        for (int nt = 0; nt < 4; ++nt)
#pragma unroll
            for (int r = 0; r < 4; ++r) {
                float p = __expf(s_acc[nt][r] - m_i[r]);
                s_acc[nt][r] = p;
                rs[r] += p;
            }
#pragma unroll
        for (int off = 1; off < 16; off <<= 1)
#pragma unroll
            for (int r = 0; r < 4; ++r)
                rs[r] += __shfl_xor(rs[r], off, 64);
#pragma unroll
        for (int r = 0; r < 4; ++r) l_i[r] = l_i[r] * alpha[r] + rs[r];

#pragma unroll
        for (int nt = 0; nt < 4; ++nt)
#pragma unroll
            for (int r = 0; r < 4; ++r)
                qp[rowb + r][nt * 16 + l16] = f2bf(s_acc[nt][r]);

#pragma unroll
        for (int nt = 0; nt < 4; ++nt)
#pragma unroll
            for (int r = 0; r < 4; ++r)
                o_acc[nt][r] *= alpha[r];

#pragma unroll
        for (int ks = 0; ks < 2; ++ks) {
            bf16x8 pa = *(const bf16x8*)&qp[wv * 16 + l16][ks * 32 + quad * 8];
#pragma unroll
            for (int nt = 0; nt < 4; ++nt) {
                bf16x8 vb = *(const bf16x8*)&v_t[nt * 16 + l16][ks * 32 + quad * 8];
                o_acc[nt] = mfma_bf16(pa, vb, o_acc[nt]);
            }
        }
    }

    // write unnormalized partials
    float* po = pO + (size_t)slot * 4096;
#pragma unroll
    for (int nt = 0; nt < 4; ++nt)
#pragma unroll
        for (int r = 0; r < 4; ++r)
            po[(rowb + r) * 64 + nt * 16 + l16] = o_acc[nt][r];
    if (l16 == 0) {
#pragma unroll
        for (int r = 0; r < 4; ++r) {
            pm[slot * 64 + rowb + r] = m_i[r];
            pl[slot * 64 + rowb + r] = l_i[r];
        }
    }
}

// ---------------------------------------------------------------------------
// Merge partials. Rows split 4-ways across blockIdx.z -> 1024 blocks.
// (round-5 passing version, unchanged)
// ---------------------------------------------------------------------------
__global__ __launch_bounds__(256) void attn_merge_kernel(
    const float* __restrict__ pO, const float* __restrict__ pm, const float* __restrict__ pl,
    float* __restrict__ out)
{
    const int qt = blockIdx.x;
    const int b  = blockIdx.y;
    const int rq = blockIdx.z;             // row quarter 0..3
    const int nc = (qt + 8) >> 3;
    const int g = qt >> 3, rr = qt & 7;
    const int s0 = b * SLOTS_PER_B + 4 * g * (g + 1) + rr * (g + 1);

    const int t   = threadIdx.x;
    const int row = rq * 16 + (t >> 4);    // 16 rows per block
    const int c0  = (t & 15) << 2;         // 16 chunks of 4 floats

    float mstar = -1e30f;
    for (int c = 0; c < nc; ++c)
        mstar = fmaxf(mstar, pm[(s0 + c) * 64 + row]);

    f32x4 acc = f32x4{0.f, 0.f, 0.f, 0.f};
    float lsum = 0.f;

    for (int c = 0; c < nc; ++c) {
        const float w = __expf(pm[(s0 + c) * 64 + row] - mstar);
        lsum += w * pl[(s0 + c) * 64 + row];
        f32x4 v = *(const f32x4*)(pO + (size_t)(s0 + c) * 4096 + row * 64 + c0);
        acc += w * v;
    }

    const float inv = 1.0f / lsum;
    float* og = out + (size_t)b * SEQ * DH + (size_t)(qt * 64 + row) * DH + c0;
    *(f32x4*)og = acc * inv;
}

extern "C" void kernel_launch(void* const* d_in, const int* in_sizes, int n_in,
                              void* d_out, int out_size, void* d_ws, size_t ws_size,
                              hipStream_t stream)
{
    (void)in_sizes; (void)n_in; (void)out_size; (void)ws_size;
    const float* q  = (const float*)d_in[0];
    const float* k  = (const float*)d_in[1];
    const float* v  = (const float*)d_in[2];
    const float* Wq = (const float*)d_in[3];
    const float* bq = (const float*)d_in[4];
    const float* Wk = (const float*)d_in[5];
    const float* bk = (const float*)d_in[6];
    const float* Wv = (const float*)d_in[7];
    const float* bv = (const float*)d_in[8];
    float* out = (float*)d_out;

    unsigned short* qh  = (unsigned short*)d_ws;
    unsigned short* kh  = qh + (size_t)NB * SEQ * DH;
    unsigned short* vhT = kh + (size_t)NB * SEQ * DH;
    float* pO = (float*)(vhT + (size_t)NB * SEQ * DH);
    float* pm = pO + (size_t)NB * SLOTS_PER_B * 4096;
    float* pl = pm + (size_t)NB * SLOTS_PER_B * 64;
    // Wfb aliases the START of pO: written by wprep, read by proj, then the
    // region is overwritten by attn_split's partials (stream-ordered, safe).
    unsigned short* Wfb = (unsigned short*)pO;

    wprep_kernel<<<dim3(16, 3), 256, 0, stream>>>(Wq, Wk, Wv, Wfb);
    proj_kernel<<<dim3(NB * SEQ / 16, 3), 256, 0, stream>>>(
        q, k, v, Wfb, bq, bk, bv, qh, kh, vhT);
    attn_split_kernel<<<dim3(8, SEQ / 64, NB), 256, 0, stream>>>(qh, kh, vhT, pO, pm, pl);
    attn_merge_kernel<<<dim3(SEQ / 64, NB, 4), 256, 0, stream>>>(pO, pm, pl, out);
}